// Round 1
// baseline (2328.558 us; speedup 1.0000x reference)
//
#include <hip/hip_runtime.h>

#define V_N    50000
#define E_N    400000
#define NEXT_N 12500
#define B_N    2
#define M_ROWS (V_N * B_N)   // 100000 GEMM rows, row = v*2 + b

typedef float  f32x4  __attribute__((ext_vector_type(4)));
typedef __bf16 bf16x8 __attribute__((ext_vector_type(8)));
typedef unsigned int u32x4 __attribute__((ext_vector_type(4)));

// ---------------- small prep kernels ----------------

__global__ void deg_kernel(const int* __restrict__ Es, const float* __restrict__ edgeOne,
                           float* __restrict__ deg) {
    int e = blockIdx.x * 256 + threadIdx.x;
    if (e < E_N) unsafeAtomicAdd(&deg[Es[e]], edgeOne[e]);
}

__global__ void deginv_kernel(float* __restrict__ deg) {
    int v = blockIdx.x * 256 + threadIdx.x;
    if (v < V_N) deg[v] = 1.0f / fmaxf(deg[v], 1.0f);
}

// invert avg-pool assignment: fine node -> (coarse row, weight)
__global__ void invmap_kernel(const int* __restrict__ idx, const float* __restrict__ val,
                              int* __restrict__ invRow, float* __restrict__ invVal) {
    int j = blockIdx.x * 256 + threadIdx.x;
    if (j < V_N) {
        int c = idx[V_N + j];   // fine node (col)
        invRow[c] = idx[j];     // coarse node (row)
        invVal[c] = val[j];
    }
}

// ---------------- edge scatter (aggregate raw features) ----------------
// S0[s*128 + b*64 + f] += adj[e] * x[(b*V + end)*64 + f]
__global__ void scatter0_kernel(const float* __restrict__ adj, const int* __restrict__ Es,
                                const int* __restrict__ Ee, const float* __restrict__ x,
                                float* __restrict__ S0) {
    int tid = blockIdx.x * 256 + threadIdx.x;   // E*32 threads
    int e = tid >> 5;
    int c = (tid & 31) * 4;                     // 0..124
    int b = c >> 6, f = c & 63;
    float a = adj[e];
    int s = Es[e], d = Ee[e];
    const f32x4 xv = *(const f32x4*)(x + (b * V_N + d) * 64 + f);
    float* dst = S0 + s * 128 + c;
    unsafeAtomicAdd(dst + 0, a * xv[0]);
    unsafeAtomicAdd(dst + 1, a * xv[1]);
    unsafeAtomicAdd(dst + 2, a * xv[2]);
    unsafeAtomicAdd(dst + 3, a * xv[3]);
}

// S1[s*256 + c] += adj[e] * OUT0[end*256 + c]   (c = b*128 + o)
__global__ void scatter1_kernel(const float* __restrict__ adj, const int* __restrict__ Es,
                                const int* __restrict__ Ee, const float* __restrict__ OUT0,
                                float* __restrict__ S1) {
    int tid = blockIdx.x * 256 + threadIdx.x;   // E*64 threads
    int e = tid >> 6;
    int c = (tid & 63) * 4;                     // 0..252
    float a = adj[e];
    int s = Es[e], d = Ee[e];
    const f32x4 xv = *(const f32x4*)(OUT0 + d * 256 + c);
    float* dst = S1 + s * 256 + c;
    unsafeAtomicAdd(dst + 0, a * xv[0]);
    unsafeAtomicAdd(dst + 1, a * xv[1]);
    unsafeAtomicAdd(dst + 2, a * xv[2]);
    unsafeAtomicAdd(dst + 3, a * xv[3]);
}

// ---------------- fused GEMM (split-bf16 MFMA) ----------------
// PHASE 0: OUT0[row][o] = leaky( [x | dinv*S0](row) @ [W0_self; W0_nb] + b0 ), K=128
// PHASE 1: atomic-pool( [OUT0 | dinv*S1 | x](row) @ [W1_self; W1_nb; W_res] + b1 + b_res ), K=320
template <int PHASE>
__global__ __launch_bounds__(256) void gemm_kernel(
    const float* __restrict__ x, const float* __restrict__ S, const float* __restrict__ IN,
    const float* __restrict__ Wa, const float* __restrict__ Wb, const float* __restrict__ Wc,
    const float* __restrict__ bias0, const float* __restrict__ bias1,
    const float* __restrict__ deginv, const int* __restrict__ invRow,
    const float* __restrict__ invVal, float* __restrict__ OUTbuf, float* __restrict__ out) {
    constexpr int K  = (PHASE == 0) ? 128 : 320;
    constexpr int KC = K / 32;

    __shared__ u32x4 ldsB[8][2][64];            // [ntile][hi/lo][lane] -> 8 bf16, 16KB
    unsigned int* ldsW = (unsigned int*)ldsB;

    const int tid  = threadIdx.x;
    const int wave = tid >> 6, lane = tid & 63;
    const int m = lane & 15, quad = lane >> 4;
    const int row0 = blockIdx.x * 64 + wave * 16;
    int grow  = row0 + m;
    int growc = grow < M_ROWS ? grow : M_ROWS - 1;
    const int v = growc >> 1, b = growc & 1;
    const float dinv = deginv[v];

    f32x4 acc[8];
#pragma unroll
    for (int i = 0; i < 8; ++i)
#pragma unroll
        for (int r = 0; r < 4; ++r) acc[i][r] = 0.0f;

    for (int kc = 0; kc < KC; ++kc) {
        if (kc) __syncthreads();
        // ---- stage W k-chunk (32 x 128) into LDS as swizzled hi/lo bf16 frags ----
#pragma unroll
        for (int it = 0; it < 16; ++it) {
            int d2 = it * 256 + tid;            // 4096 u32 total
            int jj   = d2 & 3;
            int l    = (d2 >> 2) & 63;
            int part = (d2 >> 8) & 1;
            int nt   = d2 >> 9;
            int kk = kc * 32 + ((l >> 4) * 8) + jj * 2;
            int n  = nt * 16 + (l & 15);
            const float* Wsrc; int kbase;
            if (PHASE == 0) {
                if (kk < 64) { Wsrc = Wa; kbase = 0; } else { Wsrc = Wb; kbase = 64; }
            } else {
                if (kk < 128)      { Wsrc = Wa; kbase = 0; }
                else if (kk < 256) { Wsrc = Wb; kbase = 128; }
                else               { Wsrc = Wc; kbase = 256; }
            }
            float w0 = Wsrc[(kk - kbase) * 128 + n];
            float w1 = Wsrc[(kk + 1 - kbase) * 128 + n];
            unsigned short u0, u1;
            if (part == 0) {
                u0 = __builtin_bit_cast(unsigned short, (__bf16)w0);
                u1 = __builtin_bit_cast(unsigned short, (__bf16)w1);
            } else {
                __bf16 h0 = (__bf16)w0, h1 = (__bf16)w1;
                u0 = __builtin_bit_cast(unsigned short, (__bf16)(w0 - (float)h0));
                u1 = __builtin_bit_cast(unsigned short, (__bf16)(w1 - (float)h1));
            }
            ldsW[d2] = ((unsigned int)u1 << 16) | u0;
        }

        // ---- A fragment: 8 consecutive k of this lane's row, hi/lo split ----
        int k0 = kc * 32 + quad * 8;
        const float* src; float scale = 1.0f;
        if (PHASE == 0) {
            if (k0 < 64) src = x + (b * V_N + v) * 64 + k0;
            else { src = S + v * 128 + b * 64 + (k0 - 64); scale = dinv; }
        } else {
            if (k0 < 128) src = IN + growc * 128 + k0;
            else if (k0 < 256) { src = S + growc * 128 + (k0 - 128); scale = dinv; }
            else src = x + (b * V_N + v) * 64 + (k0 - 256);
        }
        f32x4 p0 = *(const f32x4*)src;
        f32x4 p1 = *(const f32x4*)(src + 4);
        float fv[8];
#pragma unroll
        for (int j = 0; j < 4; ++j) { fv[j] = p0[j] * scale; fv[j + 4] = p1[j] * scale; }
        bf16x8 ah, al;
#pragma unroll
        for (int j = 0; j < 8; ++j) {
            __bf16 h = (__bf16)fv[j];
            ah[j] = h;
            al[j] = (__bf16)(fv[j] - (float)h);
        }
        __syncthreads();

#pragma unroll
        for (int nt = 0; nt < 8; ++nt) {
            bf16x8 bh = __builtin_bit_cast(bf16x8, ldsB[nt][0][lane]);
            bf16x8 bl = __builtin_bit_cast(bf16x8, ldsB[nt][1][lane]);
            acc[nt] = __builtin_amdgcn_mfma_f32_16x16x32_bf16(ah, bh, acc[nt], 0, 0, 0);
            acc[nt] = __builtin_amdgcn_mfma_f32_16x16x32_bf16(al, bh, acc[nt], 0, 0, 0);
            acc[nt] = __builtin_amdgcn_mfma_f32_16x16x32_bf16(ah, bl, acc[nt], 0, 0, 0);
        }
    }

    // ---- epilogue: D[row=(quad*4+r)][col=lane&15] ----
#pragma unroll
    for (int nt = 0; nt < 8; ++nt) {
        int o = nt * 16 + m;
        float bias;
        if (PHASE == 0) bias = bias0[o];
        else            bias = bias0[o] + bias1[o];
#pragma unroll
        for (int r = 0; r < 4; ++r) {
            int orow = row0 + quad * 4 + r;
            if (orow < M_ROWS) {
                float val = acc[nt][r] + bias;
                if (PHASE == 0) {
                    val = val >= 0.0f ? val : 0.2f * val;
                    OUTbuf[orow * 128 + o] = val;
                } else {
                    int vf = orow >> 1, bb = orow & 1;
                    int rr = invRow[vf];
                    if (rr >= 0)
                        unsafeAtomicAdd(&out[(bb * NEXT_N + rr) * 128 + o], invVal[vf] * val);
                }
            }
        }
    }
}

// ---------------- launch ----------------

extern "C" void kernel_launch(void* const* d_in, const int* in_sizes, int n_in,
                              void* d_out, int out_size, void* d_ws, size_t ws_size,
                              hipStream_t stream) {
    const float* x       = (const float*)d_in[0];
    const float* adj     = (const float*)d_in[1];
    const float* edgeOne = (const float*)d_in[2];
    const int*   Es      = (const int*)d_in[3];
    const int*   Ee      = (const int*)d_in[4];
    const int*   poolIdx = (const int*)d_in[5];
    const float* poolVal = (const float*)d_in[6];
    const float* W_res   = (const float*)d_in[7];
    const float* b_res   = (const float*)d_in[8];
    const float* W0s     = (const float*)d_in[9];
    const float* W0n     = (const float*)d_in[10];
    const float* b0      = (const float*)d_in[11];
    const float* W1s     = (const float*)d_in[12];
    const float* W1n     = (const float*)d_in[13];
    const float* b1      = (const float*)d_in[14];
    float* out = (float*)d_out;

    char* ws = (char*)d_ws;
    float* deg    = (float*)(ws + 0);          // V floats
    int*   invRow = (int*)  (ws + 200704);     // V ints
    float* invVal = (float*)(ws + 401408);     // V floats
    float* S0     = (float*)(ws + 602112);     // V*128 floats
    float* S1     = (float*)(ws + 26202112);   // V*256 floats
    float* OUT0   = (float*)(ws + 77402112);   // V*256 floats  (ends at ~128.6MB)

    hipMemsetAsync(deg, 0, (size_t)V_N * 4, stream);
    hipMemsetAsync(invRow, 0xFF, (size_t)V_N * 4, stream);
    hipMemsetAsync(S0, 0, (size_t)V_N * 128 * 4, stream);
    hipMemsetAsync(S1, 0, (size_t)V_N * 256 * 4, stream);
    hipMemsetAsync(d_out, 0, (size_t)out_size * 4, stream);

    deg_kernel<<<(E_N + 255) / 256, 256, 0, stream>>>(Es, edgeOne, deg);
    deginv_kernel<<<(V_N + 255) / 256, 256, 0, stream>>>(deg);
    invmap_kernel<<<(V_N + 255) / 256, 256, 0, stream>>>(poolIdx, poolVal, invRow, invVal);

    scatter0_kernel<<<(E_N * 32) / 256, 256, 0, stream>>>(adj, Es, Ee, x, S0);
    gemm_kernel<0><<<(M_ROWS + 63) / 64, 256, 0, stream>>>(
        x, S0, nullptr, W0s, W0n, nullptr, b0, nullptr, deg, invRow, invVal, OUT0, nullptr);
    scatter1_kernel<<<(E_N * 64) / 256, 256, 0, stream>>>(adj, Es, Ee, OUT0, S1);
    gemm_kernel<1><<<(M_ROWS + 63) / 64, 256, 0, stream>>>(
        x, S1, OUT0, W1s, W1n, W_res, b1, b_res, deg, invRow, invVal, nullptr, out);
}

// Round 2
// 782.685 us; speedup vs baseline: 2.9751x; 2.9751x over previous
//
#include <hip/hip_runtime.h>

#define V_N    50000
#define E_N    400000
#define NEXT_N 12500
#define B_N    2
#define M_ROWS (V_N * B_N)   // 100000 GEMM rows, row = v*2 + b

typedef float  f32x2  __attribute__((ext_vector_type(2)));
typedef float  f32x4  __attribute__((ext_vector_type(4)));
typedef __bf16 bf16x8 __attribute__((ext_vector_type(8)));
typedef unsigned int u32x4 __attribute__((ext_vector_type(4)));

// ---------------- CSR build ----------------

__global__ void hist_kernel(const int* __restrict__ Es, int* __restrict__ degi) {
    int e = blockIdx.x * 256 + threadIdx.x;
    if (e < E_N) atomicAdd(&degi[Es[e]], 1);
}

// single block, 1024 threads: exclusive-scan degi -> cur (row starts), dinv = 1/max(deg,1)
__global__ __launch_bounds__(1024) void scan_kernel(const int* __restrict__ degi,
                                                    int* __restrict__ cur,
                                                    float* __restrict__ dinv) {
    __shared__ int part[1024];
    const int t = threadIdx.x;
    const int CHUNK = 49;                    // 1024*49 = 50176 >= V_N
    int lo = t * CHUNK, hi = lo + CHUNK; if (hi > V_N) hi = V_N;
    int s = 0;
    for (int i = lo; i < hi; ++i) s += degi[i];
    part[t] = s;
    __syncthreads();
    for (int off = 1; off < 1024; off <<= 1) {
        int v = (t >= off) ? part[t - off] : 0;
        __syncthreads();
        part[t] += v;
        __syncthreads();
    }
    int run = t ? part[t - 1] : 0;           // exclusive prefix
    for (int i = lo; i < hi; ++i) {
        int d = degi[i];
        cur[i] = run;
        dinv[i] = 1.0f / (float)(d > 1 ? d : 1);
        run += d;
    }
}

__global__ void csr_kernel(const int* __restrict__ Es, const int* __restrict__ Ee,
                           const float* __restrict__ adj, int* __restrict__ cur,
                           int* __restrict__ cdst, float* __restrict__ cval) {
    int e = blockIdx.x * 256 + threadIdx.x;
    if (e < E_N) {
        int pos = atomicAdd(&cur[Es[e]], 1);
        cdst[pos] = Ee[e];
        cval[pos] = adj[e];
    }
}

// invert avg-pool assignment: fine node -> (coarse row, weight)
__global__ void invmap_kernel(const int* __restrict__ idx, const float* __restrict__ val,
                              int* __restrict__ invRow, float* __restrict__ invVal) {
    int j = blockIdx.x * 256 + threadIdx.x;
    if (j < V_N) {
        int c = idx[V_N + j];   // fine node (col)
        invRow[c] = idx[j];     // coarse node (row)
        invVal[c] = val[j];
    }
}

// ---------------- W pre-conversion into swizzled hi/lo bf16 layout ----------------
__global__ void wcvt_kernel(const float* __restrict__ Wa, const float* __restrict__ Wb,
                            const float* __restrict__ Wc, unsigned int* __restrict__ dst,
                            int KC, int phase) {
    int idx = blockIdx.x * 256 + threadIdx.x;
    if (idx >= KC * 4096) return;
    int kc = idx >> 12, d2 = idx & 4095;
    int jj = d2 & 3, l = (d2 >> 2) & 63, part = (d2 >> 8) & 1, nt = d2 >> 9;
    int kk = kc * 32 + ((l >> 4) * 8) + jj * 2;
    int n = nt * 16 + (l & 15);
    const float* Wsrc; int kbase;
    if (phase == 0) {
        if (kk < 64) { Wsrc = Wa; kbase = 0; } else { Wsrc = Wb; kbase = 64; }
    } else {
        if (kk < 128)      { Wsrc = Wa; kbase = 0; }
        else if (kk < 256) { Wsrc = Wb; kbase = 128; }
        else               { Wsrc = Wc; kbase = 256; }
    }
    float w0 = Wsrc[(kk - kbase) * 128 + n];
    float w1 = Wsrc[(kk + 1 - kbase) * 128 + n];
    unsigned short u0, u1;
    if (part == 0) {
        u0 = __builtin_bit_cast(unsigned short, (__bf16)w0);
        u1 = __builtin_bit_cast(unsigned short, (__bf16)w1);
    } else {
        __bf16 h0 = (__bf16)w0, h1 = (__bf16)w1;
        u0 = __builtin_bit_cast(unsigned short, (__bf16)(w0 - (float)h0));
        u1 = __builtin_bit_cast(unsigned short, (__bf16)(w1 - (float)h1));
    }
    dst[idx] = ((unsigned int)u1 << 16) | u0;
}

// ---------------- fused gather + GEMM (split-bf16 MFMA) ----------------
// PHASE 0: OUT0 = leaky( [x | dinv*Agg(x)] @ W0cvt + b0 ), K=128
// PHASE 1: atomic-pool( [OUT0 | dinv*Agg(OUT0) | x] @ W1cvt + b1 + b_res ), K=320
template <int PHASE>
__global__ __launch_bounds__(256) void gemm_kernel(
    const float* __restrict__ x, const float* __restrict__ IN,
    const unsigned int* __restrict__ Wcvt,
    const float* __restrict__ bias0, const float* __restrict__ bias1,
    const float* __restrict__ dinv, const int* __restrict__ cur,
    const int* __restrict__ cdst, const float* __restrict__ cval,
    const int* __restrict__ invRow, const float* __restrict__ invVal,
    float* __restrict__ OUTbuf, float* __restrict__ out) {
    constexpr int K   = (PHASE == 0) ? 128 : 320;
    constexpr int KC  = K / 32;
    constexpr int SW  = (PHASE == 0) ? 64 : 128;   // gathered S width per GEMM row
    constexpr int STR = SW + 4;                    // padded stride (floats)

    __shared__ u32x4 ldsB[8][2][64];               // 16 KB swizzled W chunk
    __shared__ float ldsS[4 * 16 * STR];           // per-wave gathered S rows

    const int tid  = threadIdx.x;
    const int wave = tid >> 6, lane = tid & 63;
    const int m = lane & 15, quad = lane >> 4;
    const int row0 = blockIdx.x * 64 + wave * 16;
    const int grow = row0 + m;
    const int growc = grow < M_ROWS ? grow : M_ROWS - 1;
    const int v = growc >> 1, b = growc & 1;

    // ---- gather: each wave fills its 16 S-rows into LDS ----
    for (int i = 0; i < 16; ++i) {
        int r = wave * 16 + i;
        int gr = blockIdx.x * 64 + r;
        int grc = gr < M_ROWS ? gr : M_ROWS - 1;
        int vv = grc >> 1, bb = grc & 1;
        int beg = vv ? cur[vv - 1] : 0;
        int end = cur[vv];
        float dv = dinv[vv];
        if (PHASE == 0) {
            float a0 = 0.0f;
            for (int e2 = beg; e2 < end; ++e2) {
                int d = cdst[e2]; float a = cval[e2];
                a0 += a * x[(bb * V_N + d) * 64 + lane];
            }
            ldsS[r * STR + lane] = a0 * dv;
        } else {
            float a0 = 0.0f, a1 = 0.0f;
            int c = lane * 2;
            for (int e2 = beg; e2 < end; ++e2) {
                int d = cdst[e2]; float a = cval[e2];
                const f32x2 s2 = *(const f32x2*)(IN + d * 256 + bb * 128 + c);
                a0 += a * s2[0]; a1 += a * s2[1];
            }
            f32x2 w2; w2[0] = a0 * dv; w2[1] = a1 * dv;
            *(f32x2*)&ldsS[r * STR + c] = w2;
        }
    }
    __syncthreads();

    f32x4 acc[8];
#pragma unroll
    for (int i = 0; i < 8; ++i)
#pragma unroll
        for (int r = 0; r < 4; ++r) acc[i][r] = 0.0f;

    for (int kc = 0; kc < KC; ++kc) {
        if (kc) __syncthreads();
        // ---- stage preconverted W chunk into LDS (plain coalesced copy) ----
        {
            const u32x4* src4 = (const u32x4*)(Wcvt + kc * 4096);
            u32x4* dst4 = (u32x4*)ldsB;
#pragma unroll
            for (int it = 0; it < 4; ++it) dst4[it * 256 + tid] = src4[it * 256 + tid];
        }

        // ---- A fragment: 8 consecutive k of this lane's row ----
        int k0 = kc * 32 + quad * 8;
        float fv[8];
        bool useLds; int lidx = 0; const float* gsrc = nullptr;
        if (PHASE == 0) {
            useLds = (k0 >= 64);
            if (useLds) lidx = (wave * 16 + m) * STR + (k0 - 64);
            else        gsrc = x + (b * V_N + v) * 64 + k0;
        } else {
            useLds = (k0 >= 128) && (k0 < 256);
            if (useLds)          lidx = (wave * 16 + m) * STR + (k0 - 128);
            else if (k0 < 128)   gsrc = IN + growc * 128 + k0;
            else                 gsrc = x + (b * V_N + v) * 64 + (k0 - 256);
        }
        if (useLds) {
            f32x4 q0 = *(const f32x4*)&ldsS[lidx];
            f32x4 q1 = *(const f32x4*)&ldsS[lidx + 4];
#pragma unroll
            for (int j = 0; j < 4; ++j) { fv[j] = q0[j]; fv[j + 4] = q1[j]; }
        } else {
            f32x4 p0 = *(const f32x4*)gsrc;
            f32x4 p1 = *(const f32x4*)(gsrc + 4);
#pragma unroll
            for (int j = 0; j < 4; ++j) { fv[j] = p0[j]; fv[j + 4] = p1[j]; }
        }
        bf16x8 ah, al;
#pragma unroll
        for (int j = 0; j < 8; ++j) {
            __bf16 h = (__bf16)fv[j];
            ah[j] = h;
            al[j] = (__bf16)(fv[j] - (float)h);
        }
        __syncthreads();

#pragma unroll
        for (int nt = 0; nt < 8; ++nt) {
            bf16x8 bh = __builtin_bit_cast(bf16x8, ldsB[nt][0][lane]);
            bf16x8 bl = __builtin_bit_cast(bf16x8, ldsB[nt][1][lane]);
            acc[nt] = __builtin_amdgcn_mfma_f32_16x16x32_bf16(ah, bh, acc[nt], 0, 0, 0);
            acc[nt] = __builtin_amdgcn_mfma_f32_16x16x32_bf16(al, bh, acc[nt], 0, 0, 0);
            acc[nt] = __builtin_amdgcn_mfma_f32_16x16x32_bf16(ah, bl, acc[nt], 0, 0, 0);
        }
    }

    // ---- epilogue: D[row=(quad*4+r)][col=lane&15] ----
#pragma unroll
    for (int nt = 0; nt < 8; ++nt) {
        int o = nt * 16 + m;
        float bias = (PHASE == 0) ? bias0[o] : (bias0[o] + bias1[o]);
#pragma unroll
        for (int r = 0; r < 4; ++r) {
            int orow = row0 + quad * 4 + r;
            if (orow < M_ROWS) {
                float val = acc[nt][r] + bias;
                if (PHASE == 0) {
                    val = val >= 0.0f ? val : 0.2f * val;
                    OUTbuf[orow * 128 + o] = val;
                } else {
                    int vf = orow >> 1, bb = orow & 1;
                    int rr = invRow[vf];
                    if (rr >= 0)
                        unsafeAtomicAdd(&out[(bb * NEXT_N + rr) * 128 + o], invVal[vf] * val);
                }
            }
        }
    }
}

// ---------------- launch ----------------

extern "C" void kernel_launch(void* const* d_in, const int* in_sizes, int n_in,
                              void* d_out, int out_size, void* d_ws, size_t ws_size,
                              hipStream_t stream) {
    const float* x       = (const float*)d_in[0];
    const float* adj     = (const float*)d_in[1];
    const int*   Es      = (const int*)d_in[3];
    const int*   Ee      = (const int*)d_in[4];
    const int*   poolIdx = (const int*)d_in[5];
    const float* poolVal = (const float*)d_in[6];
    const float* W_res   = (const float*)d_in[7];
    const float* b_res   = (const float*)d_in[8];
    const float* W0s     = (const float*)d_in[9];
    const float* W0n     = (const float*)d_in[10];
    const float* b0      = (const float*)d_in[11];
    const float* W1s     = (const float*)d_in[12];
    const float* W1n     = (const float*)d_in[13];
    const float* b1      = (const float*)d_in[14];
    float* out = (float*)d_out;

    char* ws = (char*)d_ws;
    int*   invRow = (int*)  (ws + 0);          // V ints
    float* invVal = (float*)(ws + 200704);     // V floats
    int*   degi   = (int*)  (ws + 401408);     // V ints
    float* dinv   = (float*)(ws + 602112);     // V floats
    int*   cur    = (int*)  (ws + 802816);     // V ints (row starts; mutated by csr)
    int*   cdst   = (int*)  (ws + 1003520);    // E ints
    float* cval   = (float*)(ws + 2604032);    // E floats
    unsigned int* Wc0 = (unsigned int*)(ws + 4204544);   // 16384 u32
    unsigned int* Wc1 = (unsigned int*)(ws + 4270080);   // 40960 u32
    float* OUT0   = (float*)(ws + 4433920);    // V*256 floats (ends ~55.6MB)

    hipMemsetAsync(degi, 0, (size_t)V_N * 4, stream);
    hipMemsetAsync(invRow, 0xFF, (size_t)V_N * 4, stream);
    hipMemsetAsync(d_out, 0, (size_t)out_size * 4, stream);

    hist_kernel<<<(E_N + 255) / 256, 256, 0, stream>>>(Es, degi);
    scan_kernel<<<1, 1024, 0, stream>>>(degi, cur, dinv);
    invmap_kernel<<<(V_N + 255) / 256, 256, 0, stream>>>(poolIdx, poolVal, invRow, invVal);
    csr_kernel<<<(E_N + 255) / 256, 256, 0, stream>>>(Es, Ee, adj, cur, cdst, cval);
    wcvt_kernel<<<64, 256, 0, stream>>>(W0s, W0n, nullptr, Wc0, 4, 0);
    wcvt_kernel<<<160, 256, 0, stream>>>(W1s, W1n, W_res, Wc1, 10, 1);

    gemm_kernel<0><<<(M_ROWS + 63) / 64, 256, 0, stream>>>(
        x, nullptr, Wc0, b0, nullptr, dinv, cur, cdst, cval, invRow, invVal, OUT0, nullptr);
    gemm_kernel<1><<<(M_ROWS + 63) / 64, 256, 0, stream>>>(
        x, OUT0, Wc1, b1, b_res, dinv, cur, cdst, cval, invRow, invVal, nullptr, out);
}

// Round 4
// 515.559 us; speedup vs baseline: 4.5166x; 1.5181x over previous
//
#include <hip/hip_runtime.h>

#define V_N    50000
#define E_N    400000
#define NEXT_N 12500
#define B_N    2
#define M_ROWS (V_N * B_N)   // 100000 GEMM rows, row = v*2 + b

typedef float  f32x2  __attribute__((ext_vector_type(2)));
typedef float  f32x4  __attribute__((ext_vector_type(4)));
typedef __bf16 bf16x8 __attribute__((ext_vector_type(8)));
typedef unsigned int u32x2 __attribute__((ext_vector_type(2)));
typedef unsigned int u32x4 __attribute__((ext_vector_type(4)));

__device__ __forceinline__ float bflo(unsigned int u) {
    return __builtin_bit_cast(float, u << 16);
}
__device__ __forceinline__ float bfhi(unsigned int u) {
    return __builtin_bit_cast(float, u & 0xffff0000u);
}
__device__ __forceinline__ unsigned short bf16bits(float f) {
    return __builtin_bit_cast(unsigned short, (__bf16)f);
}

// ---------------- CSR build ----------------

__global__ void hist_kernel(const int* __restrict__ Es, int* __restrict__ degi) {
    int e = blockIdx.x * 256 + threadIdx.x;
    if (e < E_N) atomicAdd(&degi[Es[e]], 1);
}

// single block, 1024 threads: exclusive-scan degi -> cur (row starts), dinv = 1/max(deg,1)
__global__ __launch_bounds__(1024) void scan_kernel(const int* __restrict__ degi,
                                                    int* __restrict__ cur,
                                                    float* __restrict__ dinv) {
    __shared__ int part[1024];
    const int t = threadIdx.x;
    const int CHUNK = 49;                    // 1024*49 = 50176 >= V_N
    int lo = t * CHUNK, hi = lo + CHUNK; if (hi > V_N) hi = V_N;
    int s = 0;
    for (int i = lo; i < hi; ++i) s += degi[i];
    part[t] = s;
    __syncthreads();
    for (int off = 1; off < 1024; off <<= 1) {
        int v = (t >= off) ? part[t - off] : 0;
        __syncthreads();
        part[t] += v;
        __syncthreads();
    }
    int run = t ? part[t - 1] : 0;           // exclusive prefix
    for (int i = lo; i < hi; ++i) {
        int d = degi[i];
        cur[i] = run;
        dinv[i] = 1.0f / (float)(d > 1 ? d : 1);
        run += d;
    }
}

__global__ void csr_kernel(const int* __restrict__ Es, const int* __restrict__ Ee,
                           const float* __restrict__ adj, int* __restrict__ cur,
                           int* __restrict__ cdst, float* __restrict__ cval) {
    int e = blockIdx.x * 256 + threadIdx.x;
    if (e < E_N) {
        int pos = atomicAdd(&cur[Es[e]], 1);
        cdst[pos] = Ee[e];
        cval[pos] = adj[e];
    }
}
// NOTE: after csr_kernel, cur[v] == row END of v; row start = cur[v-1] (0 for v=0).

// invert avg-pool assignment: fine node -> (coarse row, weight)
__global__ void invmap_kernel(const int* __restrict__ idx, const float* __restrict__ val,
                              int* __restrict__ invRow, float* __restrict__ invVal) {
    int j = blockIdx.x * 256 + threadIdx.x;
    if (j < V_N) {
        int c = idx[V_N + j];   // fine node (col)
        invRow[c] = idx[j];     // coarse node (row)
        invVal[c] = val[j];
    }
}

// x (f32, [B][V][64]) -> packed bf16 (same layout), 2 elems per u32
__global__ void xcvt_kernel(const float* __restrict__ x, unsigned int* __restrict__ xbf) {
    int i = blockIdx.x * 256 + threadIdx.x;       // 3,200,000 u32 exactly
    f32x2 p = *(const f32x2*)(x + (size_t)i * 2);
    xbf[i] = ((unsigned int)bf16bits(p[1]) << 16) | bf16bits(p[0]);
}

// ---------------- W pre-conversion into swizzled hi/lo bf16 layout ----------------
__global__ void wcvt_kernel(const float* __restrict__ Wa, const float* __restrict__ Wb,
                            const float* __restrict__ Wc, unsigned int* __restrict__ dst,
                            int KC, int phase) {
    int idx = blockIdx.x * 256 + threadIdx.x;
    if (idx >= KC * 4096) return;
    int kc = idx >> 12, d2 = idx & 4095;
    int jj = d2 & 3, l = (d2 >> 2) & 63, part = (d2 >> 8) & 1, nt = d2 >> 9;
    int kk = kc * 32 + ((l >> 4) * 8) + jj * 2;
    int n = nt * 16 + (l & 15);
    const float* Wsrc; int kbase;
    if (phase == 0) {
        if (kk < 64) { Wsrc = Wa; kbase = 0; } else { Wsrc = Wb; kbase = 64; }
    } else {
        if (kk < 128)      { Wsrc = Wa; kbase = 0; }
        else if (kk < 256) { Wsrc = Wb; kbase = 128; }
        else               { Wsrc = Wc; kbase = 256; }
    }
    float w0 = Wsrc[(kk - kbase) * 128 + n];
    float w1 = Wsrc[(kk + 1 - kbase) * 128 + n];
    unsigned short u0, u1;
    if (part == 0) {
        u0 = bf16bits(w0);
        u1 = bf16bits(w1);
    } else {
        __bf16 h0 = (__bf16)w0, h1 = (__bf16)w1;
        u0 = bf16bits(w0 - (float)h0);
        u1 = bf16bits(w1 - (float)h1);
    }
    dst[idx] = ((unsigned int)u1 << 16) | u0;
}

// ---------------- aggregation: one wave per node, edge loop unrolled x2 ----------------
// AGG0[v][c], c = b*64+f (128 wide): dinv[v] * sum_e adj * x[b][dst][f]
__global__ __launch_bounds__(256) void agg0_kernel(
    const unsigned int* __restrict__ xbf, const int* __restrict__ cur,
    const int* __restrict__ cdst, const float* __restrict__ cval,
    const float* __restrict__ dinv, float* __restrict__ AGG0) {
    int w = blockIdx.x * 4 + (threadIdx.x >> 6);  // node, 12500*4 = V_N exactly
    int lane = threadIdx.x & 63;
    int beg = w ? cur[w - 1] : 0;
    int end = cur[w];
    int c = lane * 2, b = c >> 6, f = c & 63;
    const unsigned int* src = xbf + (size_t)b * V_N * 32 + (f >> 1);
    float s0 = 0.f, s1 = 0.f, t0 = 0.f, t1 = 0.f;
    int e = beg;
    for (; e + 1 < end; e += 2) {
        int d0 = cdst[e], d1 = cdst[e + 1];
        float a0 = cval[e], a1 = cval[e + 1];
        unsigned int p0 = src[(size_t)d0 * 32];
        unsigned int p1 = src[(size_t)d1 * 32];
        s0 += a0 * bflo(p0); s1 += a0 * bfhi(p0);
        t0 += a1 * bflo(p1); t1 += a1 * bfhi(p1);
    }
    if (e < end) {
        int d0 = cdst[e]; float a0 = cval[e];
        unsigned int p0 = src[(size_t)d0 * 32];
        s0 += a0 * bflo(p0); s1 += a0 * bfhi(p0);
    }
    float dv = dinv[w];
    f32x2 r; r[0] = (s0 + t0) * dv; r[1] = (s1 + t1) * dv;
    *(f32x2*)(AGG0 + (size_t)w * 128 + c) = r;
}

// AGG1[v][c], c = b*128+o (256 wide): dinv[v] * sum_e adj * OUT0bf[dst][c]
__global__ __launch_bounds__(256) void agg1_kernel(
    const unsigned int* __restrict__ obf, const int* __restrict__ cur,
    const int* __restrict__ cdst, const float* __restrict__ cval,
    const float* __restrict__ dinv, float* __restrict__ AGG1) {
    int w = blockIdx.x * 4 + (threadIdx.x >> 6);
    int lane = threadIdx.x & 63;
    int beg = w ? cur[w - 1] : 0;
    int end = cur[w];
    float s[4] = {0, 0, 0, 0}, t[4] = {0, 0, 0, 0};
    int e = beg;
    for (; e + 1 < end; e += 2) {
        int d0 = cdst[e], d1 = cdst[e + 1];
        float a0 = cval[e], a1 = cval[e + 1];
        const u32x2 p = *(const u32x2*)(obf + (size_t)d0 * 128 + lane * 2);
        const u32x2 q = *(const u32x2*)(obf + (size_t)d1 * 128 + lane * 2);
        s[0] += a0 * bflo(p[0]); s[1] += a0 * bfhi(p[0]);
        s[2] += a0 * bflo(p[1]); s[3] += a0 * bfhi(p[1]);
        t[0] += a1 * bflo(q[0]); t[1] += a1 * bfhi(q[0]);
        t[2] += a1 * bflo(q[1]); t[3] += a1 * bfhi(q[1]);
    }
    if (e < end) {
        int d0 = cdst[e]; float a0 = cval[e];
        const u32x2 p = *(const u32x2*)(obf + (size_t)d0 * 128 + lane * 2);
        s[0] += a0 * bflo(p[0]); s[1] += a0 * bfhi(p[0]);
        s[2] += a0 * bflo(p[1]); s[3] += a0 * bfhi(p[1]);
    }
    float dv = dinv[w];
    f32x4 r;
#pragma unroll
    for (int j = 0; j < 4; ++j) r[j] = (s[j] + t[j]) * dv;
    *(f32x4*)(AGG1 + (size_t)w * 256 + lane * 4) = r;
}

// ---------------- GEMM (split-bf16 MFMA), all-streaming A ----------------
// PHASE 0: OUT0bf = bf16( leaky( [x | AGG0] @ W0cvt + b0 ) ), K=128
// PHASE 1: atomic-pool( [OUT0bf | AGG1 | x] @ W1cvt + b1 + b_res ), K=320
template <int PHASE>
__global__ __launch_bounds__(256) void gemm_kernel(
    const float* __restrict__ x, const unsigned int* __restrict__ INbf,
    const float* __restrict__ AGG, const unsigned int* __restrict__ Wcvt,
    const float* __restrict__ bias0, const float* __restrict__ bias1,
    const int* __restrict__ invRow, const float* __restrict__ invVal,
    unsigned short* __restrict__ OUTbf, float* __restrict__ out) {
    constexpr int K  = (PHASE == 0) ? 128 : 320;
    constexpr int KC = K / 32;

    __shared__ u32x4 ldsB[8][2][64];               // 16 KB swizzled W chunk

    const int tid  = threadIdx.x;
    const int wave = tid >> 6, lane = tid & 63;
    const int m = lane & 15, quad = lane >> 4;
    const int row0 = blockIdx.x * 64 + wave * 16;
    const int grow = row0 + m;
    const int growc = grow < M_ROWS ? grow : M_ROWS - 1;
    const int v = growc >> 1, b = growc & 1;

    f32x4 acc[8];
#pragma unroll
    for (int i = 0; i < 8; ++i)
#pragma unroll
        for (int r = 0; r < 4; ++r) acc[i][r] = 0.0f;

    for (int kc = 0; kc < KC; ++kc) {
        if (kc) __syncthreads();
        // ---- stage preconverted W chunk into LDS ----
        {
            const u32x4* src4 = (const u32x4*)(Wcvt + kc * 4096);
            u32x4* dst4 = (u32x4*)ldsB;
#pragma unroll
            for (int it = 0; it < 4; ++it) dst4[it * 256 + tid] = src4[it * 256 + tid];
        }

        // ---- A fragment: 8 consecutive k of this lane's row ----
        int k0 = kc * 32 + quad * 8;
        float fv[8];
        if (PHASE == 1 && k0 < 128) {
            u32x4 pk = *(const u32x4*)(INbf + (size_t)growc * 64 + (k0 >> 1));
#pragma unroll
            for (int j = 0; j < 4; ++j) { fv[2 * j] = bflo(pk[j]); fv[2 * j + 1] = bfhi(pk[j]); }
        } else {
            const float* gsrc;
            if (PHASE == 0)
                gsrc = (k0 < 64) ? x + ((size_t)b * V_N + v) * 64 + k0
                                 : AGG + (size_t)v * 128 + b * 64 + (k0 - 64);
            else
                gsrc = (k0 < 256) ? AGG + (size_t)v * 256 + b * 128 + (k0 - 128)
                                  : x + ((size_t)b * V_N + v) * 64 + (k0 - 256);
            f32x4 p0 = *(const f32x4*)gsrc;
            f32x4 p1 = *(const f32x4*)(gsrc + 4);
#pragma unroll
            for (int j = 0; j < 4; ++j) { fv[j] = p0[j]; fv[j + 4] = p1[j]; }
        }
        bf16x8 ah, al;
#pragma unroll
        for (int j = 0; j < 8; ++j) {
            __bf16 h = (__bf16)fv[j];
            ah[j] = h;
            al[j] = (__bf16)(fv[j] - (float)h);
        }
        __syncthreads();

#pragma unroll
        for (int nt = 0; nt < 8; ++nt) {
            bf16x8 bh = __builtin_bit_cast(bf16x8, ldsB[nt][0][lane]);
            bf16x8 bl = __builtin_bit_cast(bf16x8, ldsB[nt][1][lane]);
            acc[nt] = __builtin_amdgcn_mfma_f32_16x16x32_bf16(ah, bh, acc[nt], 0, 0, 0);
            acc[nt] = __builtin_amdgcn_mfma_f32_16x16x32_bf16(al, bh, acc[nt], 0, 0, 0);
            acc[nt] = __builtin_amdgcn_mfma_f32_16x16x32_bf16(ah, bl, acc[nt], 0, 0, 0);
        }
    }

    // ---- epilogue: D[row=(quad*4+r)][col=lane&15] ----
#pragma unroll
    for (int nt = 0; nt < 8; ++nt) {
        int o = nt * 16 + m;
        float bias = (PHASE == 0) ? bias0[o] : (bias0[o] + bias1[o]);
#pragma unroll
        for (int r = 0; r < 4; ++r) {
            int orow = row0 + quad * 4 + r;
            if (orow < M_ROWS) {
                float val = acc[nt][r] + bias;
                if (PHASE == 0) {
                    val = val >= 0.0f ? val : 0.2f * val;
                    OUTbf[(size_t)orow * 128 + o] = bf16bits(val);
                } else {
                    int vf = orow >> 1, bb = orow & 1;
                    int rr = invRow[vf];
                    if (rr >= 0)
                        unsafeAtomicAdd(&out[((size_t)bb * NEXT_N + rr) * 128 + o],
                                        invVal[vf] * val);
                }
            }
        }
    }
}

// ---------------- launch ----------------

extern "C" void kernel_launch(void* const* d_in, const int* in_sizes, int n_in,
                              void* d_out, int out_size, void* d_ws, size_t ws_size,
                              hipStream_t stream) {
    const float* x       = (const float*)d_in[0];
    const float* adj     = (const float*)d_in[1];
    const int*   Es      = (const int*)d_in[3];
    const int*   Ee      = (const int*)d_in[4];
    const int*   poolIdx = (const int*)d_in[5];
    const float* poolVal = (const float*)d_in[6];
    const float* W_res   = (const float*)d_in[7];
    const float* b_res   = (const float*)d_in[8];
    const float* W0s     = (const float*)d_in[9];
    const float* W0n     = (const float*)d_in[10];
    const float* b0      = (const float*)d_in[11];
    const float* W1s     = (const float*)d_in[12];
    const float* W1n     = (const float*)d_in[13];
    const float* b1      = (const float*)d_in[14];
    float* out = (float*)d_out;

    char* ws = (char*)d_ws;
    int*   invRow = (int*)  (ws + 0);            // V ints
    float* invVal = (float*)(ws + 200704);       // V floats
    int*   degi   = (int*)  (ws + 401408);       // V ints
    float* dinv   = (float*)(ws + 602112);       // V floats
    int*   cur    = (int*)  (ws + 802816);       // V ints
    int*   cdst   = (int*)  (ws + 1003520);      // E ints
    float* cval   = (float*)(ws + 2604032);      // E floats
    unsigned int* Wc0 = (unsigned int*)(ws + 4204544);   // 16384 u32
    unsigned int* Wc1 = (unsigned int*)(ws + 4270080);   // 40960 u32
    unsigned int* xbf = (unsigned int*)(ws + 4433920);   // 3.2M u32 (12.8MB)
    float* AGG0   = (float*)(ws + 17233920);     // V*128 f32 (25.6MB)
    unsigned int* OUT0bf = (unsigned int*)(ws + 42833920); // M_ROWS*128 u16 = 12.8M u16 (25.6MB)
    float* AGG1   = (float*)(ws + 68433920);     // V*256 f32 (51.2MB) -> ends ~119.6MB

    hipMemsetAsync(degi, 0, (size_t)V_N * 4, stream);
    hipMemsetAsync(invRow, 0xFF, (size_t)V_N * 4, stream);
    hipMemsetAsync(d_out, 0, (size_t)out_size * 4, stream);

    hist_kernel<<<(E_N + 255) / 256, 256, 0, stream>>>(Es, degi);
    scan_kernel<<<1, 1024, 0, stream>>>(degi, cur, dinv);
    invmap_kernel<<<(V_N + 255) / 256, 256, 0, stream>>>(poolIdx, poolVal, invRow, invVal);
    csr_kernel<<<(E_N + 255) / 256, 256, 0, stream>>>(Es, Ee, adj, cur, cdst, cval);
    wcvt_kernel<<<64, 256, 0, stream>>>(W0s, W0n, nullptr, Wc0, 4, 0);
    wcvt_kernel<<<160, 256, 0, stream>>>(W1s, W1n, W_res, Wc1, 10, 1);
    xcvt_kernel<<<12500, 256, 0, stream>>>(x, xbf);

    agg0_kernel<<<12500, 256, 0, stream>>>(xbf, cur, cdst, cval, dinv, AGG0);
    gemm_kernel<0><<<(M_ROWS + 63) / 64, 256, 0, stream>>>(
        x, nullptr, AGG0, Wc0, b0, nullptr, invRow, invVal,
        (unsigned short*)OUT0bf, nullptr);
    agg1_kernel<<<12500, 256, 0, stream>>>(OUT0bf, cur, cdst, cval, dinv, AGG1);
    gemm_kernel<1><<<(M_ROWS + 63) / 64, 256, 0, stream>>>(
        x, OUT0bf, AGG1, Wc1, b1, b_res, invRow, invVal,
        nullptr, out);
}

// Round 8
// 371.251 us; speedup vs baseline: 6.2722x; 1.3887x over previous
//
#include <hip/hip_runtime.h>

#define V_N    50000
#define E_N    400000
#define NEXT_N 12500
#define B_N    2
#define M_ROWS (V_N * B_N)   // planar GEMM rows: row = b*V_N + v

typedef float  f32x2  __attribute__((ext_vector_type(2)));
typedef float  f32x4  __attribute__((ext_vector_type(4)));
typedef __bf16 bf16x8 __attribute__((ext_vector_type(8)));
typedef unsigned int u32x2 __attribute__((ext_vector_type(2)));
typedef unsigned int u32x4 __attribute__((ext_vector_type(4)));

__device__ __forceinline__ float bflo(unsigned int u) {
    return __builtin_bit_cast(float, u << 16);
}
__device__ __forceinline__ float bfhi(unsigned int u) {
    return __builtin_bit_cast(float, u & 0xffff0000u);
}
__device__ __forceinline__ unsigned short bf16bits(float f) {
    return __builtin_bit_cast(unsigned short, (__bf16)f);
}

// ---------------- CSR build ----------------

__global__ void hist_kernel(const int* __restrict__ Es, int* __restrict__ degi) {
    int e = blockIdx.x * 256 + threadIdx.x;
    if (e < E_N) atomicAdd(&degi[Es[e]], 1);
}

__global__ __launch_bounds__(1024) void scan_kernel(const int* __restrict__ degi,
                                                    int* __restrict__ cur,
                                                    float* __restrict__ dinv) {
    __shared__ int part[1024];
    const int t = threadIdx.x;
    const int CHUNK = 49;                    // 1024*49 = 50176 >= V_N
    int lo = t * CHUNK, hi = lo + CHUNK; if (hi > V_N) hi = V_N;
    int s = 0;
    for (int i = lo; i < hi; ++i) s += degi[i];
    part[t] = s;
    __syncthreads();
    for (int off = 1; off < 1024; off <<= 1) {
        int v = (t >= off) ? part[t - off] : 0;
        __syncthreads();
        part[t] += v;
        __syncthreads();
    }
    int run = t ? part[t - 1] : 0;           // exclusive prefix
    for (int i = lo; i < hi; ++i) {
        int d = degi[i];
        cur[i] = run;
        dinv[i] = 1.0f / (float)(d > 1 ? d : 1);
        run += d;
    }
}

__global__ void csr_kernel(const int* __restrict__ Es, const int* __restrict__ Ee,
                           const float* __restrict__ adj, int* __restrict__ cur,
                           int* __restrict__ cdst, float* __restrict__ cval) {
    int e = blockIdx.x * 256 + threadIdx.x;
    if (e < E_N) {
        int pos = atomicAdd(&cur[Es[e]], 1);
        cdst[pos] = Ee[e];
        cval[pos] = adj[e];
    }
}
// after csr_kernel: cur[v] == row END of v; row start = cur[v-1] (0 for v=0).

__global__ void invmap_kernel(const int* __restrict__ idx, const float* __restrict__ val,
                              int* __restrict__ invRow, float* __restrict__ invVal) {
    int j = blockIdx.x * 256 + threadIdx.x;
    if (j < V_N) {
        int c = idx[V_N + j];   // fine node (col)
        invRow[c] = idx[j];     // coarse node (row)
        invVal[c] = val[j];
    }
}

// x (f32, [B][V][64]) -> packed bf16 (same planar layout), 2 elems per u32
__global__ void xcvt_kernel(const float* __restrict__ x, unsigned int* __restrict__ xbf) {
    int i = blockIdx.x * 256 + threadIdx.x;       // 3,200,000 u32 exactly
    f32x2 p = *(const f32x2*)(x + (size_t)i * 2);
    xbf[i] = ((unsigned int)bf16bits(p[1]) << 16) | bf16bits(p[0]);
}

// ---------------- W pre-conversion into MFMA-frag-swizzled bf16 ----------------
// dst u32 index: ((kc*8 + nt)*64 + lane)*4 + jj  holds bf16(W[k][n]),bf16(W[k+1][n])
// with k = kc*32 + (lane>>4)*8 + jj*2, n = nt*16 + (lane&15)
__global__ void wcvt_kernel(const float* __restrict__ Wa, const float* __restrict__ Wb,
                            const float* __restrict__ Wc, unsigned int* __restrict__ dst,
                            int KC, int phase) {
    int idx = blockIdx.x * 256 + threadIdx.x;
    if (idx >= KC * 2048) return;
    int kc = idx >> 11;
    int jj = idx & 3, lane = (idx >> 2) & 63, nt = (idx >> 8) & 7;
    int kk = kc * 32 + ((lane >> 4) * 8) + jj * 2;
    int n  = nt * 16 + (lane & 15);
    const float* Wsrc; int kbase;
    if (phase == 0) {
        if (kk < 64) { Wsrc = Wa; kbase = 0; } else { Wsrc = Wb; kbase = 64; }
    } else {
        if (kk < 128)      { Wsrc = Wa; kbase = 0; }
        else if (kk < 256) { Wsrc = Wb; kbase = 128; }
        else               { Wsrc = Wc; kbase = 256; }
    }
    float w0 = Wsrc[(kk - kbase) * 128 + n];
    float w1 = Wsrc[(kk + 1 - kbase) * 128 + n];
    dst[idx] = ((unsigned int)bf16bits(w1) << 16) | bf16bits(w0);
}

// ---------------- aggregation: one wave per node ----------------
// AGG0bf[(b*V+v)*32 + f/2] (u32, packed bf16): dinv[v] * sum_e adj * x[b][dst][f,f+1]
__global__ __launch_bounds__(256) void agg0_kernel(
    const unsigned int* __restrict__ xbf, const int* __restrict__ cur,
    const int* __restrict__ cdst, const float* __restrict__ cval,
    const float* __restrict__ dinv, unsigned int* __restrict__ AGG0bf) {
    int w = blockIdx.x * 4 + (threadIdx.x >> 6);  // node
    int lane = threadIdx.x & 63;
    int beg = w ? cur[w - 1] : 0;
    int end = cur[w];
    int b = lane >> 5;                   // lanes 0-31: b=0, 32-63: b=1
    int u = lane & 31;                   // u32 index within 64-feat row
    const unsigned int* src = xbf + (size_t)b * V_N * 32 + u;
    float s0 = 0.f, s1 = 0.f, t0 = 0.f, t1 = 0.f;
    int e = beg;
    for (; e + 1 < end; e += 2) {
        int d0 = cdst[e], d1 = cdst[e + 1];
        float a0 = cval[e], a1 = cval[e + 1];
        unsigned int p0 = src[(size_t)d0 * 32];
        unsigned int p1 = src[(size_t)d1 * 32];
        s0 += a0 * bflo(p0); s1 += a0 * bfhi(p0);
        t0 += a1 * bflo(p1); t1 += a1 * bfhi(p1);
    }
    if (e < end) {
        int d0 = cdst[e]; float a0 = cval[e];
        unsigned int p0 = src[(size_t)d0 * 32];
        s0 += a0 * bflo(p0); s1 += a0 * bfhi(p0);
    }
    float dv = dinv[w];
    AGG0bf[((size_t)b * V_N + w) * 32 + u] =
        ((unsigned int)bf16bits((s1 + t1) * dv) << 16) | bf16bits((s0 + t0) * dv);
}

// AGG1bf[(b*V+v)*64 + o/2] (u32): dinv[v] * sum_e adj * OUT0bf[b][dst][o..o+3]
__global__ __launch_bounds__(256) void agg1_kernel(
    const unsigned int* __restrict__ obf, const int* __restrict__ cur,
    const int* __restrict__ cdst, const float* __restrict__ cval,
    const float* __restrict__ dinv, unsigned int* __restrict__ AGG1bf) {
    int w = blockIdx.x * 4 + (threadIdx.x >> 6);
    int lane = threadIdx.x & 63;
    int beg = w ? cur[w - 1] : 0;
    int end = cur[w];
    int b = lane >> 5;
    int u = (lane & 31) * 2;             // u32 offset within 128-feat row (4 bf16)
    const unsigned int* src = obf + (size_t)b * V_N * 64 + u;
    float s[4] = {0, 0, 0, 0}, t[4] = {0, 0, 0, 0};
    int e = beg;
    for (; e + 1 < end; e += 2) {
        int d0 = cdst[e], d1 = cdst[e + 1];
        float a0 = cval[e], a1 = cval[e + 1];
        const u32x2 p = *(const u32x2*)(src + (size_t)d0 * 64);
        const u32x2 q = *(const u32x2*)(src + (size_t)d1 * 64);
        s[0] += a0 * bflo(p[0]); s[1] += a0 * bfhi(p[0]);
        s[2] += a0 * bflo(p[1]); s[3] += a0 * bfhi(p[1]);
        t[0] += a1 * bflo(q[0]); t[1] += a1 * bfhi(q[0]);
        t[2] += a1 * bflo(q[1]); t[3] += a1 * bfhi(q[1]);
    }
    if (e < end) {
        int d0 = cdst[e]; float a0 = cval[e];
        const u32x2 p = *(const u32x2*)(src + (size_t)d0 * 64);
        s[0] += a0 * bflo(p[0]); s[1] += a0 * bfhi(p[0]);
        s[2] += a0 * bflo(p[1]); s[3] += a0 * bfhi(p[1]);
    }
    float dv = dinv[w];
    u32x2 r;
    r[0] = ((unsigned int)bf16bits((s[1] + t[1]) * dv) << 16) | bf16bits((s[0] + t[0]) * dv);
    r[1] = ((unsigned int)bf16bits((s[3] + t[3]) * dv) << 16) | bf16bits((s[2] + t[2]) * dv);
    *(u32x2*)(AGG1bf + ((size_t)b * V_N + w) * 64 + u) = r;
}

// ---------------- GEMM: W resident in LDS, barrier-free K-loop, bf16 MFMA ----------------
// PHASE 0: OUT0bf = bf16( leaky( [xbf | AGG0bf] @ W + b0 ) ), K=128
// PHASE 1: pool-store( [OUT0bf | AGG1bf | xbf] @ W + b1 + b_res ), K=320
template <int PHASE>
__global__ __launch_bounds__(256) void gemm_kernel(
    const unsigned int* __restrict__ xbf, const unsigned int* __restrict__ INbf,
    const unsigned int* __restrict__ AGGbf, const unsigned int* __restrict__ Wcvt,
    const float* __restrict__ bias0, const float* __restrict__ bias1,
    const int* __restrict__ invRow, const float* __restrict__ invVal,
    unsigned short* __restrict__ OUTbf, float* __restrict__ out) {
    constexpr int K  = (PHASE == 0) ? 128 : 320;
    constexpr int KC = K / 32;

    __shared__ unsigned int ldsW[KC * 2048];       // 32 KB (P0) / 80 KB (P1)

    const int tid  = threadIdx.x;
    const int wave = tid >> 6, lane = tid & 63;
    const int m = lane & 15, quad = lane >> 4;

    // stage full W once
    {
        const u32x4* src4 = (const u32x4*)Wcvt;
        u32x4* dst4 = (u32x4*)ldsW;
#pragma unroll
        for (int it = 0; it < 2 * KC; ++it) dst4[it * 256 + tid] = src4[it * 256 + tid];
    }
    __syncthreads();

    const int rowA  = blockIdx.x * 64 + wave * 16 + m;       // planar row = b*V + v
    const int rowAc = rowA < M_ROWS ? rowA : M_ROWS - 1;

    f32x4 acc[8];
#pragma unroll
    for (int i = 0; i < 8; ++i)
#pragma unroll
        for (int r = 0; r < 4; ++r) acc[i][r] = 0.0f;

#pragma unroll
    for (int kc = 0; kc < KC; ++kc) {
        int k0 = kc * 32 + quad * 8;
        const unsigned int* abase;
        if (PHASE == 0) {
            abase = (k0 < 64) ? xbf + (size_t)rowAc * 32 + (k0 >> 1)
                              : AGGbf + (size_t)rowAc * 32 + ((k0 - 64) >> 1);
        } else {
            if (k0 < 128)      abase = INbf + (size_t)rowAc * 64 + (k0 >> 1);
            else if (k0 < 256) abase = AGGbf + (size_t)rowAc * 64 + ((k0 - 128) >> 1);
            else               abase = xbf + (size_t)rowAc * 32 + ((k0 - 256) >> 1);
        }
        bf16x8 av = __builtin_bit_cast(bf16x8, *(const u32x4*)abase);
#pragma unroll
        for (int nt = 0; nt < 8; ++nt) {
            bf16x8 bv = __builtin_bit_cast(
                bf16x8, *(const u32x4*)&ldsW[(kc * 8 + nt) * 256 + lane * 4]);
            acc[nt] = __builtin_amdgcn_mfma_f32_16x16x32_bf16(av, bv, acc[nt], 0, 0, 0);
        }
    }

    // ---- epilogue: D[row=(quad*4+r)][col=nt*16+m] ----
    const int rowq = blockIdx.x * 64 + wave * 16 + quad * 4; // first row of this quad
    if (PHASE == 0) {
#pragma unroll
        for (int nt = 0; nt < 8; ++nt) {
            int o = nt * 16 + m;
            float bias = bias0[o];
#pragma unroll
            for (int r = 0; r < 4; ++r) {
                int orow = rowq + r;
                if (orow < M_ROWS) {
                    float val = acc[nt][r] + bias;
                    val = val >= 0.0f ? val : 0.2f * val;
                    OUTbf[(size_t)orow * 128 + o] = bf16bits(val);
                }
            }
        }
    } else {
        // quad's 4 rows = 4 consecutive fine nodes of one batch (rowq divisible by 4)
        int b = rowq >= V_N;
        int vq = rowq - b * V_N;
        int rr0 = -2, rr1 = -2, rr2 = -2, rr3 = -2;
        float w0 = 0, w1 = 0, w2 = 0, w3 = 0;
        bool inb = (rowq + 3) < M_ROWS;
        if (inb) {
            rr0 = invRow[vq];     w0 = invVal[vq];
            rr1 = invRow[vq + 1]; w1 = invVal[vq + 1];
            rr2 = invRow[vq + 2]; w2 = invVal[vq + 2];
            rr3 = invRow[vq + 3]; w3 = invVal[vq + 3];
        }
        bool uniform = inb && (rr0 >= 0) && (rr0 == rr1) && (rr0 == rr2) && (rr0 == rr3);
#pragma unroll
        for (int nt = 0; nt < 8; ++nt) {
            int o = nt * 16 + m;
            float bias = bias0[o] + bias1[o];
            if (uniform) {
                float pooled = w0 * (acc[nt][0] + bias) + w1 * (acc[nt][1] + bias) +
                               w2 * (acc[nt][2] + bias) + w3 * (acc[nt][3] + bias);
                out[((size_t)b * NEXT_N + rr0) * 128 + o] = pooled;
            } else {
#pragma unroll
                for (int r = 0; r < 4; ++r) {
                    int orow = rowq + r;
                    if (orow < M_ROWS) {
                        int bb = orow >= V_N;
                        int vf = orow - bb * V_N;
                        int rrr = invRow[vf];
                        float www = invVal[vf];
                        if (rrr >= 0)
                            unsafeAtomicAdd(&out[((size_t)bb * NEXT_N + rrr) * 128 + o],
                                            www * (acc[nt][r] + bias));
                    }
                }
            }
        }
    }
}

// ---------------- launch ----------------

extern "C" void kernel_launch(void* const* d_in, const int* in_sizes, int n_in,
                              void* d_out, int out_size, void* d_ws, size_t ws_size,
                              hipStream_t stream) {
    const float* x       = (const float*)d_in[0];
    const float* adj     = (const float*)d_in[1];
    const int*   Es      = (const int*)d_in[3];
    const int*   Ee      = (const int*)d_in[4];
    const int*   poolIdx = (const int*)d_in[5];
    const float* poolVal = (const float*)d_in[6];
    const float* W_res   = (const float*)d_in[7];
    const float* b_res   = (const float*)d_in[8];
    const float* W0s     = (const float*)d_in[9];
    const float* W0n     = (const float*)d_in[10];
    const float* b0      = (const float*)d_in[11];
    const float* W1s     = (const float*)d_in[12];
    const float* W1n     = (const float*)d_in[13];
    const float* b1      = (const float*)d_in[14];
    float* out = (float*)d_out;

    char* ws = (char*)d_ws;
    int*   invRow = (int*)  (ws + 0);            // V ints
    float* invVal = (float*)(ws + 200704);       // V floats
    int*   degi   = (int*)  (ws + 401408);       // V ints
    float* dinv   = (float*)(ws + 602112);       // V floats
    int*   cur    = (int*)  (ws + 802816);       // V ints
    int*   cdst   = (int*)  (ws + 1003520);      // E ints
    float* cval   = (float*)(ws + 2604032);      // E floats
    unsigned int* Wc0 = (unsigned int*)(ws + 4204544);   // 8192 u32
    unsigned int* Wc1 = (unsigned int*)(ws + 4237312);   // 20480 u32
    unsigned int* xbf    = (unsigned int*)(ws + 4319232);  // 3.2M u32 (12.8MB)
    unsigned int* AGG0bf = (unsigned int*)(ws + 17119232); // 3.2M u32 (12.8MB)
    unsigned int* OUT0bf = (unsigned int*)(ws + 29919232); // 6.4M u32 (25.6MB)
    unsigned int* AGG1bf = (unsigned int*)(ws + 55519232); // 6.4M u32 (25.6MB) -> ends ~81.1MB

    hipMemsetAsync(degi, 0, (size_t)V_N * 4, stream);
    hipMemsetAsync(invRow, 0xFF, (size_t)V_N * 4, stream);
    hipMemsetAsync(d_out, 0, (size_t)out_size * 4, stream);

    hist_kernel<<<(E_N + 255) / 256, 256, 0, stream>>>(Es, degi);
    scan_kernel<<<1, 1024, 0, stream>>>(degi, cur, dinv);
    invmap_kernel<<<(V_N + 255) / 256, 256, 0, stream>>>(poolIdx, poolVal, invRow, invVal);
    csr_kernel<<<(E_N + 255) / 256, 256, 0, stream>>>(Es, Ee, adj, cur, cdst, cval);
    wcvt_kernel<<<32, 256, 0, stream>>>(W0s, W0n, nullptr, Wc0, 4, 0);
    wcvt_kernel<<<80, 256, 0, stream>>>(W1s, W1n, W_res, Wc1, 10, 1);
    xcvt_kernel<<<12500, 256, 0, stream>>>(x, xbf);

    agg0_kernel<<<12500, 256, 0, stream>>>(xbf, cur, cdst, cval, dinv, AGG0bf);
    gemm_kernel<0><<<(M_ROWS + 63) / 64, 256, 0, stream>>>(
        xbf, nullptr, AGG0bf, Wc0, b0, nullptr, invRow, invVal,
        (unsigned short*)OUT0bf, nullptr);
    agg1_kernel<<<12500, 256, 0, stream>>>(OUT0bf, cur, cdst, cval, dinv, AGG1bf);
    gemm_kernel<1><<<(M_ROWS + 63) / 64, 256, 0, stream>>>(
        xbf, OUT0bf, AGG1bf, Wc1, b1, b_res, invRow, invVal,
        nullptr, out);
}

// Round 10
// 252.104 us; speedup vs baseline: 9.2365x; 1.4726x over previous
//
#include <hip/hip_runtime.h>

#define V_N    50000
#define E_N    400000
#define NEXT_N 12500
#define B_N    2
#define M_ROWS (V_N * B_N)   // planar GEMM rows: row = b*V_N + v
#define NSBLK  196           // scan blocks: 196*256 = 50176 >= V_N

typedef float  f32x2  __attribute__((ext_vector_type(2)));
typedef float  f32x4  __attribute__((ext_vector_type(4)));
typedef __bf16 bf16x8 __attribute__((ext_vector_type(8)));
typedef unsigned int u32x2 __attribute__((ext_vector_type(2)));
typedef unsigned int u32x4 __attribute__((ext_vector_type(4)));

__device__ __forceinline__ float bflo(unsigned int u) {
    return __builtin_bit_cast(float, u << 16);
}
__device__ __forceinline__ float bfhi(unsigned int u) {
    return __builtin_bit_cast(float, u & 0xffff0000u);
}
__device__ __forceinline__ unsigned short bf16bits(float f) {
    return __builtin_bit_cast(unsigned short, (__bf16)f);
}

// ---------------- W swizzle helper ----------------
__device__ __forceinline__ void wcvt_one(int idx, int phase,
                                         const float* Wa, const float* Wb, const float* Wc,
                                         unsigned int* dst) {
    int kc = idx >> 11;
    int jj = idx & 3, lane = (idx >> 2) & 63, nt = (idx >> 8) & 7;
    int kk = kc * 32 + ((lane >> 4) * 8) + jj * 2;
    int n  = nt * 16 + (lane & 15);
    const float* Wsrc; int kbase;
    if (phase == 0) {
        if (kk < 64) { Wsrc = Wa; kbase = 0; } else { Wsrc = Wb; kbase = 64; }
    } else {
        if (kk < 128)      { Wsrc = Wa; kbase = 0; }
        else if (kk < 256) { Wsrc = Wb; kbase = 128; }
        else               { Wsrc = Wc; kbase = 256; }
    }
    float w0 = Wsrc[(kk - kbase) * 128 + n];
    float w1 = Wsrc[(kk + 1 - kbase) * 128 + n];
    dst[idx] = ((unsigned int)bf16bits(w1) << 16) | bf16bits(w0);
}

// ---------------- fused prep: xcvt | hist | invmap | wcvt0 | wcvt1 ----------------
// grid = 12500 + 1563 + 196 + 32 + 80 = 14371 blocks
__global__ void prep_kernel(const float* __restrict__ x, unsigned int* __restrict__ xbf,
                            const int* __restrict__ Es, int* __restrict__ degi,
                            const int* __restrict__ poolIdx, const float* __restrict__ poolVal,
                            int* __restrict__ invRow, float* __restrict__ invVal,
                            const float* __restrict__ W0s, const float* __restrict__ W0n,
                            const float* __restrict__ W1s, const float* __restrict__ W1n,
                            const float* __restrict__ Wres,
                            unsigned int* __restrict__ Wc0, unsigned int* __restrict__ Wc1) {
    int blk = blockIdx.x, t = threadIdx.x;
    if (blk < 12500) {                       // xcvt: 3.2M u32 exactly
        int i = blk * 256 + t;
        f32x2 p = *(const f32x2*)(x + (size_t)i * 2);
        xbf[i] = ((unsigned int)bf16bits(p[1]) << 16) | bf16bits(p[0]);
    } else if (blk < 14063) {                // hist
        int e = (blk - 12500) * 256 + t;
        if (e < E_N) atomicAdd(&degi[Es[e]], 1);
    } else if (blk < 14259) {                // invmap
        int j = (blk - 14063) * 256 + t;
        if (j < V_N) {
            int c = poolIdx[V_N + j];        // fine node
            invRow[c] = poolIdx[j];          // coarse node
            invVal[c] = poolVal[j];
        }
    } else if (blk < 14291) {                // wcvt phase 0 (8192 u32)
        wcvt_one((blk - 14259) * 256 + t, 0, W0s, W0n, nullptr, Wc0);
    } else {                                 // wcvt phase 1 (20480 u32)
        wcvt_one((blk - 14291) * 256 + t, 1, W1s, W1n, Wres, Wc1);
    }
}

// ---------------- parallel scan of degi -> cur (row starts) + dinv ----------------
__global__ void partial_kernel(const int* __restrict__ degi, int* __restrict__ part) {
    __shared__ int sh[256];
    int t = threadIdx.x, i = blockIdx.x * 256 + t;
    sh[t] = (i < V_N) ? degi[i] : 0;
    __syncthreads();
    for (int off = 128; off > 0; off >>= 1) {
        if (t < off) sh[t] += sh[t + off];
        __syncthreads();
    }
    if (t == 0) part[blockIdx.x] = sh[0];
}

__global__ void scanpart_kernel(const int* __restrict__ part, int* __restrict__ bofs) {
    __shared__ int sh[256];
    int t = threadIdx.x;
    int p = (t < NSBLK) ? part[t] : 0;
    sh[t] = p;
    __syncthreads();
    for (int off = 1; off < 256; off <<= 1) {
        int v = (t >= off) ? sh[t - off] : 0;
        __syncthreads();
        sh[t] += v;
        __syncthreads();
    }
    if (t < NSBLK) bofs[t] = sh[t] - p;      // exclusive block offset
}

__global__ void emit_kernel(const int* __restrict__ degi, const int* __restrict__ bofs,
                            int* __restrict__ cur, float* __restrict__ dinv) {
    __shared__ int sh[256];
    int t = threadIdx.x, i = blockIdx.x * 256 + t;
    int d = (i < V_N) ? degi[i] : 0;
    sh[t] = d;
    __syncthreads();
    for (int off = 1; off < 256; off <<= 1) {
        int v = (t >= off) ? sh[t - off] : 0;
        __syncthreads();
        sh[t] += v;
        __syncthreads();
    }
    if (i < V_N) {
        cur[i] = bofs[blockIdx.x] + sh[t] - d;   // exclusive prefix = row start
        dinv[i] = 1.0f / (float)(d > 1 ? d : 1);
    }
}

__global__ void csr_kernel(const int* __restrict__ Es, const int* __restrict__ Ee,
                           const float* __restrict__ adj, int* __restrict__ cur,
                           int* __restrict__ cdst, float* __restrict__ cval) {
    int e = blockIdx.x * 256 + threadIdx.x;
    if (e < E_N) {
        int pos = atomicAdd(&cur[Es[e]], 1);
        cdst[pos] = Ee[e];
        cval[pos] = adj[e];
    }
}
// after csr_kernel: cur[v] == row END of v; row start = cur[v-1] (0 for v=0).

// ---------------- aggregation: one wave per node, 8-edge batched gathers ----------------
// AGG0bf[(b*V+v)*32 + f/2]: dinv[v] * sum_e adj * x[b][dst][f,f+1]
__global__ __launch_bounds__(256) void agg0_kernel(
    const unsigned int* __restrict__ xbf, const int* __restrict__ cur,
    const int* __restrict__ cdst, const float* __restrict__ cval,
    const float* __restrict__ dinv, unsigned int* __restrict__ AGG0bf) {
    int w = blockIdx.x * 4 + (threadIdx.x >> 6);  // node
    int lane = threadIdx.x & 63;
    int beg = w ? cur[w - 1] : 0;
    int end = cur[w];
    int b = lane >> 5, u = lane & 31;
    const unsigned int* src = xbf + (size_t)b * V_N * 32 + u;
    float s0 = 0.f, s1 = 0.f;
    for (int base = beg; base < end; base += 8) {
        int li = base + (lane & 7);
        bool lv = li < end;
        int dk = lv ? cdst[li] : 0;
        float ak = lv ? cval[li] : 0.0f;
        unsigned int pv[8]; float av[8];
#pragma unroll
        for (int j = 0; j < 8; ++j) {
            int dj = __shfl(dk, j);
            av[j] = __shfl(ak, j);
            pv[j] = src[(size_t)dj * 32];
        }
#pragma unroll
        for (int j = 0; j < 8; ++j) { s0 += av[j] * bflo(pv[j]); s1 += av[j] * bfhi(pv[j]); }
    }
    float dv = dinv[w];
    AGG0bf[((size_t)b * V_N + w) * 32 + u] =
        ((unsigned int)bf16bits(s1 * dv) << 16) | bf16bits(s0 * dv);
}

// AGG1bf[(b*V+v)*64 + o/2]: dinv[v] * sum_e adj * OUT0bf[b][dst][o..o+3]
__global__ __launch_bounds__(256) void agg1_kernel(
    const unsigned int* __restrict__ obf, const int* __restrict__ cur,
    const int* __restrict__ cdst, const float* __restrict__ cval,
    const float* __restrict__ dinv, unsigned int* __restrict__ AGG1bf) {
    int w = blockIdx.x * 4 + (threadIdx.x >> 6);
    int lane = threadIdx.x & 63;
    int beg = w ? cur[w - 1] : 0;
    int end = cur[w];
    int b = lane >> 5;
    int u = (lane & 31) * 2;
    const unsigned int* src = obf + (size_t)b * V_N * 64 + u;
    float s[4] = {0, 0, 0, 0};
    for (int base = beg; base < end; base += 8) {
        int li = base + (lane & 7);
        bool lv = li < end;
        int dk = lv ? cdst[li] : 0;
        float ak = lv ? cval[li] : 0.0f;
        u32x2 pv[8]; float av[8];
#pragma unroll
        for (int j = 0; j < 8; ++j) {
            int dj = __shfl(dk, j);
            av[j] = __shfl(ak, j);
            pv[j] = *(const u32x2*)(src + (size_t)dj * 64);
        }
#pragma unroll
        for (int j = 0; j < 8; ++j) {
            s[0] += av[j] * bflo(pv[j][0]); s[1] += av[j] * bfhi(pv[j][0]);
            s[2] += av[j] * bflo(pv[j][1]); s[3] += av[j] * bfhi(pv[j][1]);
        }
    }
    float dv = dinv[w];
    u32x2 r;
    r[0] = ((unsigned int)bf16bits(s[1] * dv) << 16) | bf16bits(s[0] * dv);
    r[1] = ((unsigned int)bf16bits(s[3] * dv) << 16) | bf16bits(s[2] * dv);
    *(u32x2*)(AGG1bf + ((size_t)b * V_N + w) * 64 + u) = r;
}

// ---------------- GEMM: W resident in LDS, barrier-free K-loop, bf16 MFMA ----------------
// PHASE 0: OUT0bf = bf16( leaky( [xbf | AGG0bf] @ W + b0 ) ), K=128
// PHASE 1: pool-store( [OUT0bf | AGG1bf | xbf] @ W + b1 + b_res ), K=320
template <int PHASE>
__global__ __launch_bounds__(256) void gemm_kernel(
    const unsigned int* __restrict__ xbf, const unsigned int* __restrict__ INbf,
    const unsigned int* __restrict__ AGGbf, const unsigned int* __restrict__ Wcvt,
    const float* __restrict__ bias0, const float* __restrict__ bias1,
    const int* __restrict__ invRow, const float* __restrict__ invVal,
    unsigned short* __restrict__ OUTbf, float* __restrict__ out) {
    constexpr int K  = (PHASE == 0) ? 128 : 320;
    constexpr int KC = K / 32;

    __shared__ unsigned int ldsW[KC * 2048];       // 32 KB (P0) / 80 KB (P1)

    const int tid  = threadIdx.x;
    const int wave = tid >> 6, lane = tid & 63;
    const int m = lane & 15, quad = lane >> 4;

    // stage full W once
    {
        const u32x4* src4 = (const u32x4*)Wcvt;
        u32x4* dst4 = (u32x4*)ldsW;
#pragma unroll
        for (int it = 0; it < 2 * KC; ++it) dst4[it * 256 + tid] = src4[it * 256 + tid];
    }
    __syncthreads();

    const int rowA  = blockIdx.x * 64 + wave * 16 + m;       // planar row = b*V + v
    const int rowAc = rowA < M_ROWS ? rowA : M_ROWS - 1;

    f32x4 acc[8];
#pragma unroll
    for (int i = 0; i < 8; ++i)
#pragma unroll
        for (int r = 0; r < 4; ++r) acc[i][r] = 0.0f;

#pragma unroll
    for (int kc = 0; kc < KC; ++kc) {
        int k0 = kc * 32 + quad * 8;
        const unsigned int* abase;
        if (PHASE == 0) {
            abase = (k0 < 64) ? xbf + (size_t)rowAc * 32 + (k0 >> 1)
                              : AGGbf + (size_t)rowAc * 32 + ((k0 - 64) >> 1);
        } else {
            if (k0 < 128)      abase = INbf + (size_t)rowAc * 64 + (k0 >> 1);
            else if (k0 < 256) abase = AGGbf + (size_t)rowAc * 64 + ((k0 - 128) >> 1);
            else               abase = xbf + (size_t)rowAc * 32 + ((k0 - 256) >> 1);
        }
        bf16x8 av = __builtin_bit_cast(bf16x8, *(const u32x4*)abase);
#pragma unroll
        for (int nt = 0; nt < 8; ++nt) {
            bf16x8 bv = __builtin_bit_cast(
                bf16x8, *(const u32x4*)&ldsW[(kc * 8 + nt) * 256 + lane * 4]);
            acc[nt] = __builtin_amdgcn_mfma_f32_16x16x32_bf16(av, bv, acc[nt], 0, 0, 0);
        }
    }

    // ---- epilogue: D[row=(quad*4+r)][col=nt*16+m] ----
    const int rowq = blockIdx.x * 64 + wave * 16 + quad * 4; // first row of this quad
    if (PHASE == 0) {
#pragma unroll
        for (int nt = 0; nt < 8; ++nt) {
            int o = nt * 16 + m;
            float bias = bias0[o];
#pragma unroll
            for (int r = 0; r < 4; ++r) {
                int orow = rowq + r;
                if (orow < M_ROWS) {
                    float val = acc[nt][r] + bias;
                    val = val >= 0.0f ? val : 0.2f * val;
                    OUTbf[(size_t)orow * 128 + o] = bf16bits(val);
                }
            }
        }
    } else {
        // quad's 4 rows = 4 consecutive fine nodes of one batch (rowq divisible by 4)
        int b = rowq >= V_N;
        int vq = rowq - b * V_N;
        int rr0 = -2, rr1 = -2, rr2 = -2, rr3 = -2;
        float w0 = 0, w1 = 0, w2 = 0, w3 = 0;
        bool inb = (rowq + 3) < M_ROWS;
        if (inb) {
            rr0 = invRow[vq];     w0 = invVal[vq];
            rr1 = invRow[vq + 1]; w1 = invVal[vq + 1];
            rr2 = invRow[vq + 2]; w2 = invVal[vq + 2];
            rr3 = invRow[vq + 3]; w3 = invVal[vq + 3];
        }
        bool uniform = inb && (rr0 >= 0) && (rr0 == rr1) && (rr0 == rr2) && (rr0 == rr3);
#pragma unroll
        for (int nt = 0; nt < 8; ++nt) {
            int o = nt * 16 + m;
            float bias = bias0[o] + bias1[o];
            if (uniform) {
                float pooled = w0 * (acc[nt][0] + bias) + w1 * (acc[nt][1] + bias) +
                               w2 * (acc[nt][2] + bias) + w3 * (acc[nt][3] + bias);
                out[((size_t)b * NEXT_N + rr0) * 128 + o] = pooled;
            } else {
#pragma unroll
                for (int r = 0; r < 4; ++r) {
                    int orow = rowq + r;
                    if (orow < M_ROWS) {
                        int bb = orow >= V_N;
                        int vf = orow - bb * V_N;
                        int rrr = invRow[vf];
                        float www = invVal[vf];
                        if (rrr >= 0)
                            unsafeAtomicAdd(&out[((size_t)bb * NEXT_N + rrr) * 128 + o],
                                            www * (acc[nt][r] + bias));
                    }
                }
            }
        }
    }
}

// ---------------- launch ----------------

extern "C" void kernel_launch(void* const* d_in, const int* in_sizes, int n_in,
                              void* d_out, int out_size, void* d_ws, size_t ws_size,
                              hipStream_t stream) {
    const float* x       = (const float*)d_in[0];
    const float* adj     = (const float*)d_in[1];
    const int*   Es      = (const int*)d_in[3];
    const int*   Ee      = (const int*)d_in[4];
    const int*   poolIdx = (const int*)d_in[5];
    const float* poolVal = (const float*)d_in[6];
    const float* W_res   = (const float*)d_in[7];
    const float* b_res   = (const float*)d_in[8];
    const float* W0s     = (const float*)d_in[9];
    const float* W0n     = (const float*)d_in[10];
    const float* b0      = (const float*)d_in[11];
    const float* W1s     = (const float*)d_in[12];
    const float* W1n     = (const float*)d_in[13];
    const float* b1      = (const float*)d_in[14];
    float* out = (float*)d_out;

    char* ws = (char*)d_ws;
    int*   invRow = (int*)  (ws + 0);            // V ints
    float* invVal = (float*)(ws + 200704);       // V floats
    int*   degi   = (int*)  (ws + 401408);       // V ints
    float* dinv   = (float*)(ws + 602112);       // V floats
    int*   cur    = (int*)  (ws + 802816);       // V ints
    int*   cdst   = (int*)  (ws + 1003520);      // E ints
    float* cval   = (float*)(ws + 2604032);      // E floats
    unsigned int* Wc0 = (unsigned int*)(ws + 4204544);   // 8192 u32
    unsigned int* Wc1 = (unsigned int*)(ws + 4237312);   // 20480 u32
    unsigned int* xbf    = (unsigned int*)(ws + 4319232);  // 3.2M u32 (12.8MB)
    unsigned int* AGG0bf = (unsigned int*)(ws + 17119232); // 3.2M u32 (12.8MB)
    unsigned int* OUT0bf = (unsigned int*)(ws + 29919232); // 6.4M u32 (25.6MB)
    unsigned int* AGG1bf = (unsigned int*)(ws + 55519232); // 6.4M u32 (25.6MB)
    int*   part   = (int*)  (ws + 81119232);     // NSBLK ints
    int*   bofs   = (int*)  (ws + 81120256);     // NSBLK ints -> ends ~81.1MB

    hipMemsetAsync(degi, 0, (size_t)V_N * 4, stream);
    hipMemsetAsync(invRow, 0xFF, (size_t)V_N * 4, stream);
    hipMemsetAsync(d_out, 0, (size_t)out_size * 4, stream);

    prep_kernel<<<14371, 256, 0, stream>>>(x, xbf, Es, degi, poolIdx, poolVal,
                                           invRow, invVal, W0s, W0n, W1s, W1n, W_res,
                                           Wc0, Wc1);
    partial_kernel<<<NSBLK, 256, 0, stream>>>(degi, part);
    scanpart_kernel<<<1, 256, 0, stream>>>(part, bofs);
    emit_kernel<<<NSBLK, 256, 0, stream>>>(degi, bofs, cur, dinv);
    csr_kernel<<<(E_N + 255) / 256, 256, 0, stream>>>(Es, Ee, adj, cur, cdst, cval);

    agg0_kernel<<<12500, 256, 0, stream>>>(xbf, cur, cdst, cval, dinv, AGG0bf);
    gemm_kernel<0><<<(M_ROWS + 63) / 64, 256, 0, stream>>>(
        xbf, nullptr, AGG0bf, Wc0, b0, nullptr, invRow, invVal,
        (unsigned short*)OUT0bf, nullptr);
    agg1_kernel<<<12500, 256, 0, stream>>>(OUT0bf, cur, cdst, cval, dinv, AGG1bf);
    gemm_kernel<1><<<(M_ROWS + 63) / 64, 256, 0, stream>>>(
        xbf, OUT0bf, AGG1bf, Wc1, b1, b_res, invRow, invVal,
        nullptr, out);
}